// Round 2
// baseline (7018.753 us; speedup 1.0000x reference)
//
#include <hip/hip_runtime.h>
#include <math.h>

#define NN 16384
#define DD 512
#define KSEL 10
#define MCAND 16   // fp32 filter keeps top-16 per column-half; fp64 rescore picks exact top-10

// ---------------- K1: t = tanh(3 * (emb[idx] @ W^T + b)) ----------------
// 64x64 output tile, 256 threads, 4x4 per thread, BK=32.
__global__ __launch_bounds__(256) void k_transform(
    const int* __restrict__ idx, const float* __restrict__ emb,
    const float* __restrict__ W, const float* __restrict__ bias,
    float* __restrict__ t_out)
{
    __shared__ float As[32][68];   // [k][m]
    __shared__ float Bs[32][68];   // [k][n]
    const int tid = threadIdx.x;
    const int tx = tid & 15, ty = tid >> 4;
    const int m0 = (blockIdx.x >> 3) << 6;
    const int n0 = (blockIdx.x & 7) << 6;

    float acc[4][4] = {};

    const int f0 = tid, f1 = tid + 256;
    const int r0 = f0 >> 3, c0_ = f0 & 7;
    const int r1 = f1 >> 3, c1_ = f1 & 7;
    const int ga0 = idx[m0 + r0];
    const int ga1 = idx[m0 + r1];

    for (int kc = 0; kc < DD; kc += 32) {
        const float4 a0 = *(const float4*)&emb[(size_t)ga0 * DD + kc + (c0_ << 2)];
        const float4 a1 = *(const float4*)&emb[(size_t)ga1 * DD + kc + (c1_ << 2)];
        const float4 b0 = *(const float4*)&W[(size_t)(n0 + r0) * DD + kc + (c0_ << 2)];
        const float4 b1 = *(const float4*)&W[(size_t)(n0 + r1) * DD + kc + (c1_ << 2)];
        As[(c0_<<2)+0][r0] = a0.x; As[(c0_<<2)+1][r0] = a0.y;
        As[(c0_<<2)+2][r0] = a0.z; As[(c0_<<2)+3][r0] = a0.w;
        As[(c1_<<2)+0][r1] = a1.x; As[(c1_<<2)+1][r1] = a1.y;
        As[(c1_<<2)+2][r1] = a1.z; As[(c1_<<2)+3][r1] = a1.w;
        Bs[(c0_<<2)+0][r0] = b0.x; Bs[(c0_<<2)+1][r0] = b0.y;
        Bs[(c0_<<2)+2][r0] = b0.z; Bs[(c0_<<2)+3][r0] = b0.w;
        Bs[(c1_<<2)+0][r1] = b1.x; Bs[(c1_<<2)+1][r1] = b1.y;
        Bs[(c1_<<2)+2][r1] = b1.z; Bs[(c1_<<2)+3][r1] = b1.w;
        __syncthreads();
        #pragma unroll
        for (int k = 0; k < 32; ++k) {
            const float4 a = *(const float4*)&As[k][ty << 2];
            const float4 b = *(const float4*)&Bs[k][tx << 2];
            const float av[4] = {a.x, a.y, a.z, a.w};
            const float bv[4] = {b.x, b.y, b.z, b.w};
            #pragma unroll
            for (int i = 0; i < 4; ++i)
                #pragma unroll
                for (int j = 0; j < 4; ++j)
                    acc[i][j] = fmaf(av[i], bv[j], acc[i][j]);
        }
        __syncthreads();
    }

    #pragma unroll
    for (int i = 0; i < 4; ++i) {
        const int m = m0 + (ty << 2) + i;
        float o[4];
        #pragma unroll
        for (int j = 0; j < 4; ++j) {
            const int n = n0 + (tx << 2) + j;
            o[j] = tanhf(3.0f * (acc[i][j] + bias[n]));
        }
        *(float4*)&t_out[(size_t)m * DD + n0 + (tx << 2)] =
            make_float4(o[0], o[1], o[2], o[3]);
    }
}

// ------------- K2: fp32 sim filter — exact-in-fp32 running top-16 per half -------------
__global__ __launch_bounds__(256) void k_sim_topk(
    const float* __restrict__ t, float* __restrict__ pv, int* __restrict__ pi)
{
    __shared__ float As[32][68];
    __shared__ float Bs[32][68];
    __shared__ float cv[64][64];
    __shared__ int   ci[64][64];
    __shared__ float topv[64][MCAND];
    __shared__ int   topi[64][MCAND];
    __shared__ float thresh[64];
    __shared__ int   ccnt[64];

    const int tid = threadIdx.x;
    const int tx = tid & 15, ty = tid >> 4;
    const int m0 = (blockIdx.x >> 1) << 6;
    const int s  = blockIdx.x & 1;

    if (tid < 64) {
        thresh[tid] = -1e30f;
        ccnt[tid] = 0;
        for (int j = 0; j < MCAND; ++j) { topv[tid][j] = -1e30f; topi[tid][j] = 0x7fffffff; }
    }
    __syncthreads();

    const int f0 = tid, f1 = tid + 256;
    const int r0 = f0 >> 3, c0_ = f0 & 7;
    const int r1 = f1 >> 3, c1_ = f1 & 7;

    const int c_begin = s * (NN / 2);
    const int c_end = c_begin + (NN / 2);

    for (int c0 = c_begin; c0 < c_end; c0 += 64) {
        float acc[4][4] = {};
        for (int kc = 0; kc < DD; kc += 32) {
            const float4 a0 = *(const float4*)&t[(size_t)(m0 + r0) * DD + kc + (c0_ << 2)];
            const float4 a1 = *(const float4*)&t[(size_t)(m0 + r1) * DD + kc + (c1_ << 2)];
            const float4 b0 = *(const float4*)&t[(size_t)(c0 + r0) * DD + kc + (c0_ << 2)];
            const float4 b1 = *(const float4*)&t[(size_t)(c0 + r1) * DD + kc + (c1_ << 2)];
            As[(c0_<<2)+0][r0] = a0.x; As[(c0_<<2)+1][r0] = a0.y;
            As[(c0_<<2)+2][r0] = a0.z; As[(c0_<<2)+3][r0] = a0.w;
            As[(c1_<<2)+0][r1] = a1.x; As[(c1_<<2)+1][r1] = a1.y;
            As[(c1_<<2)+2][r1] = a1.z; As[(c1_<<2)+3][r1] = a1.w;
            Bs[(c0_<<2)+0][r0] = b0.x; Bs[(c0_<<2)+1][r0] = b0.y;
            Bs[(c0_<<2)+2][r0] = b0.z; Bs[(c0_<<2)+3][r0] = b0.w;
            Bs[(c1_<<2)+0][r1] = b1.x; Bs[(c1_<<2)+1][r1] = b1.y;
            Bs[(c1_<<2)+2][r1] = b1.z; Bs[(c1_<<2)+3][r1] = b1.w;
            __syncthreads();
            #pragma unroll
            for (int k = 0; k < 32; ++k) {
                const float4 a = *(const float4*)&As[k][ty << 2];
                const float4 b = *(const float4*)&Bs[k][tx << 2];
                const float av[4] = {a.x, a.y, a.z, a.w};
                const float bv[4] = {b.x, b.y, b.z, b.w};
                #pragma unroll
                for (int i = 0; i < 4; ++i)
                    #pragma unroll
                    for (int j = 0; j < 4; ++j)
                        acc[i][j] = fmaf(av[i], bv[j], acc[i][j]);
            }
            __syncthreads();
        }
        // ---- drain: candidate collection (fast path = 1 compare) ----
        #pragma unroll
        for (int i = 0; i < 4; ++i) {
            const int r = (ty << 2) + i;
            const float th = thresh[r];
            #pragma unroll
            for (int j = 0; j < 4; ++j) {
                const float v = acc[i][j];
                if (v >= th) {   // per-tile max 64 candidates == capacity
                    const int p = atomicAdd(&ccnt[r], 1);
                    cv[r][p] = v;
                    ci[r][p] = c0 + (tx << 2) + j;
                }
            }
        }
        __syncthreads();
        // ---- merge: one thread per row ----
        if (tid < 64) {
            const int r = tid;
            const int cnt = ccnt[r];
            for (int q = 0; q < cnt; ++q) {
                const float v = cv[r][q];
                const int c = ci[r][q];
                if (v > topv[r][MCAND-1] ||
                    (v == topv[r][MCAND-1] && c < topi[r][MCAND-1])) {
                    int p = MCAND - 1;
                    while (p > 0 && (v > topv[r][p-1] ||
                                     (v == topv[r][p-1] && c < topi[r][p-1]))) {
                        topv[r][p] = topv[r][p-1];
                        topi[r][p] = topi[r][p-1];
                        --p;
                    }
                    topv[r][p] = v;
                    topi[r][p] = c;
                }
            }
            ccnt[r] = 0;
            thresh[r] = topv[r][MCAND-1];
        }
        __syncthreads();
    }

    if (tid < 64) {
        const size_t base = ((size_t)(((m0 >> 6) << 1) + s) * 64 + tid) * MCAND;
        for (int j = 0; j < MCAND; ++j) {
            pv[base + j] = topv[tid][j];
            pi[base + j] = topi[tid][j];
        }
    }
}

// ------------- K3: fp64 rescore of 32 candidates/row, exact top-10, scatter -------------
// One wave per row. Lane holds 8 floats of t[r]; per candidate: f64 dot + wave reduce.
__global__ __launch_bounds__(256) void k_rescore(
    const float* __restrict__ t, const int* __restrict__ pi,
    float* __restrict__ out)
{
    const int wave = threadIdx.x >> 6;
    const int lane = threadIdx.x & 63;
    const int r = blockIdx.x * 4 + wave;

    const float4 a0 = *(const float4*)&t[(size_t)r * DD + lane * 8];
    const float4 a1 = *(const float4*)&t[(size_t)r * DD + lane * 8 + 4];

    const int mblk = r >> 6, row = r & 63;
    const size_t b0 = ((size_t)((mblk << 1) + 0) * 64 + row) * MCAND;
    const size_t b1 = ((size_t)((mblk << 1) + 1) * 64 + row) * MCAND;

    double bestv[KSEL];
    int    besti[KSEL];
    #pragma unroll
    for (int j = 0; j < KSEL; ++j) { bestv[j] = -1e300; besti[j] = 0x7fffffff; }

    for (int q = 0; q < 2 * MCAND; ++q) {
        const int c = (q < MCAND) ? pi[b0 + q] : pi[b1 + q - MCAND];
        const float4 v0 = *(const float4*)&t[(size_t)c * DD + lane * 8];
        const float4 v1 = *(const float4*)&t[(size_t)c * DD + lane * 8 + 4];
        double s = 0.0;
        s += (double)a0.x * (double)v0.x;
        s += (double)a0.y * (double)v0.y;
        s += (double)a0.z * (double)v0.z;
        s += (double)a0.w * (double)v0.w;
        s += (double)a1.x * (double)v1.x;
        s += (double)a1.y * (double)v1.y;
        s += (double)a1.z * (double)v1.z;
        s += (double)a1.w * (double)v1.w;
        #pragma unroll
        for (int off = 32; off > 0; off >>= 1)
            s += __shfl_down(s, off, 64);
        // lane 0 holds the exact (to ~1e-13) similarity; maintain top-10 there
        if (s > bestv[KSEL-1] || (s == bestv[KSEL-1] && c < besti[KSEL-1])) {
            int p = KSEL - 1;
            while (p > 0 && (s > bestv[p-1] || (s == bestv[p-1] && c < besti[p-1]))) {
                bestv[p] = bestv[p-1]; besti[p] = besti[p-1]; --p;
            }
            bestv[p] = s; besti[p] = c;
        }
    }

    if (lane == 0) {
        #pragma unroll
        for (int j = 0; j < KSEL; ++j)
            out[(size_t)besti[j] * NN + r] = 1.0f;
    }
}

extern "C" void kernel_launch(void* const* d_in, const int* in_sizes, int n_in,
                              void* d_out, int out_size, void* d_ws, size_t ws_size,
                              hipStream_t stream) {
    const int*   idx  = (const int*)d_in[0];
    const float* emb  = (const float*)d_in[1];
    const float* linw = (const float*)d_in[2];
    const float* linb = (const float*)d_in[3];
    float* out = (float*)d_out;

    // ws layout: t [N*D f32] = 32 MB, pv [N*2*16 f32] = 2 MB, pi [N*2*16 i32] = 2 MB
    float* t  = (float*)d_ws;
    float* pv = (float*)((char*)d_ws + (size_t)NN * DD * sizeof(float));
    int*   pi = (int*)((char*)d_ws + (size_t)NN * DD * sizeof(float)
                                   + (size_t)NN * 2 * MCAND * sizeof(float));

    (void)hipMemsetAsync(d_out, 0, (size_t)NN * (size_t)NN * sizeof(float), stream);

    k_transform<<<dim3(256 * 8), dim3(256), 0, stream>>>(idx, emb, linw, linb, t);
    k_sim_topk<<<dim3(512), dim3(256), 0, stream>>>(t, pv, pi);
    k_rescore<<<dim3(NN / 4), dim3(256), 0, stream>>>(t, pi, out);
}

// Round 3
// 2885.389 us; speedup vs baseline: 2.4325x; 2.4325x over previous
//
#include <hip/hip_runtime.h>
#include <hip/hip_bf16.h>
#include <math.h>

#define NN 16384
#define DD 512
#define KSEL 10
#define MCAND 16   // filter keeps top-16 per column-split; fp64 rescore picks exact top-10
#define NSPLIT 4   // column splits for k_sim_topk

typedef __bf16 bf16x8 __attribute__((ext_vector_type(8)));
typedef float  f32x4  __attribute__((ext_vector_type(4)));

#define GLOAD_LDS16(gsrc, ldst) \
    __builtin_amdgcn_global_load_lds( \
        (const __attribute__((address_space(1))) void*)(gsrc), \
        (__attribute__((address_space(3))) void*)(ldst), 16, 0, 0)

// ---------------- K1: t = tanh(3 * (emb[idx] @ W^T + b)); also emit bf16 copy ----------------
__global__ __launch_bounds__(256) void k_transform(
    const int* __restrict__ idx, const float* __restrict__ emb,
    const float* __restrict__ W, const float* __restrict__ bias,
    float* __restrict__ t_out, unsigned short* __restrict__ tb_out)
{
    __shared__ float As[32][68];   // [k][m]
    __shared__ float Bs[32][68];   // [k][n]
    const int tid = threadIdx.x;
    const int tx = tid & 15, ty = tid >> 4;
    const int m0 = (blockIdx.x >> 3) << 6;
    const int n0 = (blockIdx.x & 7) << 6;

    float acc[4][4] = {};

    const int f0 = tid, f1 = tid + 256;
    const int r0 = f0 >> 3, c0_ = f0 & 7;
    const int r1 = f1 >> 3, c1_ = f1 & 7;
    const int ga0 = idx[m0 + r0];
    const int ga1 = idx[m0 + r1];

    for (int kc = 0; kc < DD; kc += 32) {
        const float4 a0 = *(const float4*)&emb[(size_t)ga0 * DD + kc + (c0_ << 2)];
        const float4 a1 = *(const float4*)&emb[(size_t)ga1 * DD + kc + (c1_ << 2)];
        const float4 b0 = *(const float4*)&W[(size_t)(n0 + r0) * DD + kc + (c0_ << 2)];
        const float4 b1 = *(const float4*)&W[(size_t)(n0 + r1) * DD + kc + (c1_ << 2)];
        As[(c0_<<2)+0][r0] = a0.x; As[(c0_<<2)+1][r0] = a0.y;
        As[(c0_<<2)+2][r0] = a0.z; As[(c0_<<2)+3][r0] = a0.w;
        As[(c1_<<2)+0][r1] = a1.x; As[(c1_<<2)+1][r1] = a1.y;
        As[(c1_<<2)+2][r1] = a1.z; As[(c1_<<2)+3][r1] = a1.w;
        Bs[(c0_<<2)+0][r0] = b0.x; Bs[(c0_<<2)+1][r0] = b0.y;
        Bs[(c0_<<2)+2][r0] = b0.z; Bs[(c0_<<2)+3][r0] = b0.w;
        Bs[(c1_<<2)+0][r1] = b1.x; Bs[(c1_<<2)+1][r1] = b1.y;
        Bs[(c1_<<2)+2][r1] = b1.z; Bs[(c1_<<2)+3][r1] = b1.w;
        __syncthreads();
        #pragma unroll
        for (int k = 0; k < 32; ++k) {
            const float4 a = *(const float4*)&As[k][ty << 2];
            const float4 b = *(const float4*)&Bs[k][tx << 2];
            const float av[4] = {a.x, a.y, a.z, a.w};
            const float bv[4] = {b.x, b.y, b.z, b.w};
            #pragma unroll
            for (int i = 0; i < 4; ++i)
                #pragma unroll
                for (int j = 0; j < 4; ++j)
                    acc[i][j] = fmaf(av[i], bv[j], acc[i][j]);
        }
        __syncthreads();
    }

    #pragma unroll
    for (int i = 0; i < 4; ++i) {
        const int m = m0 + (ty << 2) + i;
        float o[4];
        union { __hip_bfloat16 h[4]; ushort4 u; } cc;
        #pragma unroll
        for (int j = 0; j < 4; ++j) {
            const int n = n0 + (tx << 2) + j;
            o[j] = tanhf(3.0f * (acc[i][j] + bias[n]));
            cc.h[j] = __float2bfloat16(o[j]);
        }
        *(float4*)&t_out[(size_t)m * DD + n0 + (tx << 2)] =
            make_float4(o[0], o[1], o[2], o[3]);
        *(ushort4*)&tb_out[(size_t)m * DD + n0 + (tx << 2)] = cc.u;
    }
}

// ------------- K2: bf16 MFMA sim filter — running top-16 per (128-row, 4096-col) block -------------
// 128x128 tile, 4 waves in 2x2 grid, each wave 64x64 via 4x4 frags of 16x16x32 bf16.
// LDS tiles row-major [128][64 bf16] with XOR swizzle byte^=((row&7)<<4); staged via
// global_load_lds (linear dest) + pre-swizzled per-lane global source (involution).
__global__ __launch_bounds__(256) void k_sim_topk(
    const unsigned short* __restrict__ tb, unsigned short* __restrict__ pi)
{
    __shared__ __align__(16) unsigned short Abuf[128 * 64];  // 16 KB
    __shared__ __align__(16) unsigned short Bbuf[128 * 64];  // 16 KB
    __shared__ float          cv[128][16];                   // 8 KB
    __shared__ unsigned short ci[128][16];                   // 4 KB
    __shared__ float          topv[128][MCAND];              // 8 KB
    __shared__ unsigned short topi[128][MCAND];              // 4 KB
    __shared__ float          thresh[128];
    __shared__ int            cnt[128];

    const int tid  = threadIdx.x;
    const int wave = tid >> 6;
    const int lane = tid & 63;
    const int wr   = wave >> 1;   // wave row  (0..1) -> rows  wr*64..
    const int wc   = wave & 1;    // wave col  (0..1) -> cols  wc*64..
    const int m0 = (blockIdx.x >> 2) << 7;     // 128 row-blocks
    const int s  = blockIdx.x & 3;             // column split
    const int c_begin = s * (NN / NSPLIT);

    if (tid < 128) {
        thresh[tid] = -1e30f;
        cnt[tid] = 0;
        #pragma unroll
        for (int j = 0; j < MCAND; ++j) { topv[tid][j] = -1e30f; topi[tid][j] = 0xFFFFu; }
    }
    __syncthreads();

    // staging constants: issue ai covers rows [ai*8, ai*8+8), lane l -> row ai*8+(l>>3),
    // 16B-col (l&7); swizzled source col = (l&7) ^ (l>>3)  (row&7 == l>>3).
    const int lr8 = lane >> 3;
    const int scx = ((lane & 7) ^ lr8) << 4;          // swizzled byte offset in 128B row-chunk
    const char* tbb = (const char*)tb;

    for (int ct = 0; ct < (NN / NSPLIT) / 128; ++ct) {
        const int c0 = c_begin + (ct << 7);
        f32x4 acc[4][4] = {};

        for (int kc = 0; kc < DD; kc += 64) {
            const size_t kb = (size_t)(kc << 1);  // byte offset in a tb row
            // stage A (rows m0..m0+127) and B (rows c0..c0+127): 4 issues each per wave
            #pragma unroll
            for (int i = 0; i < 4; ++i) {
                const int ai = (wave << 2) + i;
                GLOAD_LDS16(tbb + (size_t)(m0 + (ai << 3) + lr8) * 1024 + kb + scx,
                            (char*)Abuf + (ai << 10));
            }
            #pragma unroll
            for (int i = 0; i < 4; ++i) {
                const int ai = (wave << 2) + i;
                GLOAD_LDS16(tbb + (size_t)(c0 + (ai << 3) + lr8) * 1024 + kb + scx,
                            (char*)Bbuf + (ai << 10));
            }
            __syncthreads();

            #pragma unroll
            for (int ks = 0; ks < 2; ++ks) {
                bf16x8 af[4], bf[4];
                #pragma unroll
                for (int m = 0; m < 4; ++m) {
                    const int row = (wr << 6) + (m << 4) + (lane & 15);
                    const int corig = (ks << 2) + (lane >> 4);
                    af[m] = *(const bf16x8*)((const char*)Abuf +
                            (row << 7) + ((corig ^ (row & 7)) << 4));
                }
                #pragma unroll
                for (int n = 0; n < 4; ++n) {
                    const int row = (wc << 6) + (n << 4) + (lane & 15);
                    const int corig = (ks << 2) + (lane >> 4);
                    bf[n] = *(const bf16x8*)((const char*)Bbuf +
                            (row << 7) + ((corig ^ (row & 7)) << 4));
                }
                #pragma unroll
                for (int m = 0; m < 4; ++m)
                    #pragma unroll
                    for (int n = 0; n < 4; ++n)
                        acc[m][n] = __builtin_amdgcn_mfma_f32_16x16x32_bf16(
                            af[m], bf[n], acc[m][n], 0, 0, 0);
            }
            __syncthreads();
        }

        // ---- drain: 8 rounds of 16 columns (one n-frag of one wave-column) ----
        #pragma unroll
        for (int rnd = 0; rnd < 8; ++rnd) {
            const int wcr = rnd >> 2, nf = rnd & 3;
            if (wc == wcr) {
                #pragma unroll
                for (int m = 0; m < 4; ++m) {
                    #pragma unroll
                    for (int j = 0; j < 4; ++j) {
                        const int row = (wr << 6) + (m << 4) + ((lane >> 4) << 2) + j;
                        const float v = acc[m][nf][j];
                        if (v >= thresh[row]) {   // capacity 16 == round width
                            const int p = atomicAdd(&cnt[row], 1);
                            cv[row][p] = v;
                            ci[row][p] = (unsigned short)(c0 + (wc << 6) + (nf << 4) + (lane & 15));
                        }
                    }
                }
            }
            __syncthreads();
            if (tid < 128) {
                const int r = tid;
                const int n_ = cnt[r];
                for (int q = 0; q < n_; ++q) {
                    const float v = cv[r][q];
                    const unsigned short c = ci[r][q];
                    if (v > topv[r][MCAND-1] ||
                        (v == topv[r][MCAND-1] && c < topi[r][MCAND-1])) {
                        int p = MCAND - 1;
                        while (p > 0 && (v > topv[r][p-1] ||
                                         (v == topv[r][p-1] && c < topi[r][p-1]))) {
                            topv[r][p] = topv[r][p-1];
                            topi[r][p] = topi[r][p-1];
                            --p;
                        }
                        topv[r][p] = v;
                        topi[r][p] = c;
                    }
                }
                cnt[r] = 0;
                thresh[r] = topv[r][MCAND-1];
            }
            __syncthreads();
        }
    }

    if (tid < 128) {
        const size_t base = ((size_t)blockIdx.x * 128 + tid) * MCAND;
        #pragma unroll
        for (int j = 0; j < MCAND; ++j)
            pi[base + j] = topi[tid][j];
    }
}

// ------------- K3: fp64 rescore of 64 candidates/row, exact top-10, scatter -------------
__global__ __launch_bounds__(256) void k_rescore(
    const float* __restrict__ t, const unsigned short* __restrict__ pi,
    float* __restrict__ out)
{
    const int wave = threadIdx.x >> 6;
    const int lane = threadIdx.x & 63;
    const int r = blockIdx.x * 4 + wave;

    const float4 a0 = *(const float4*)&t[(size_t)r * DD + lane * 8];
    const float4 a1 = *(const float4*)&t[(size_t)r * DD + lane * 8 + 4];

    const int row_block = r >> 7, local = r & 127;

    double bestv[KSEL];
    int    besti[KSEL];
    #pragma unroll
    for (int j = 0; j < KSEL; ++j) { bestv[j] = -1e300; besti[j] = 0x7fffffff; }

    for (int sp = 0; sp < NSPLIT; ++sp) {
        const size_t base = ((size_t)(row_block * NSPLIT + sp) * 128 + local) * MCAND;
        for (int q = 0; q < MCAND; ++q) {
            const int c = (int)pi[base + q];
            const float4 v0 = *(const float4*)&t[(size_t)c * DD + lane * 8];
            const float4 v1 = *(const float4*)&t[(size_t)c * DD + lane * 8 + 4];
            double sdot = 0.0;
            sdot += (double)a0.x * (double)v0.x;
            sdot += (double)a0.y * (double)v0.y;
            sdot += (double)a0.z * (double)v0.z;
            sdot += (double)a0.w * (double)v0.w;
            sdot += (double)a1.x * (double)v1.x;
            sdot += (double)a1.y * (double)v1.y;
            sdot += (double)a1.z * (double)v1.z;
            sdot += (double)a1.w * (double)v1.w;
            #pragma unroll
            for (int off = 32; off > 0; off >>= 1)
                sdot += __shfl_down(sdot, off, 64);
            if (sdot > bestv[KSEL-1] || (sdot == bestv[KSEL-1] && c < besti[KSEL-1])) {
                int p = KSEL - 1;
                while (p > 0 && (sdot > bestv[p-1] ||
                                 (sdot == bestv[p-1] && c < besti[p-1]))) {
                    bestv[p] = bestv[p-1]; besti[p] = besti[p-1]; --p;
                }
                bestv[p] = sdot; besti[p] = c;
            }
        }
    }

    if (lane == 0) {
        #pragma unroll
        for (int j = 0; j < KSEL; ++j)
            out[(size_t)besti[j] * NN + r] = 1.0f;
    }
}

extern "C" void kernel_launch(void* const* d_in, const int* in_sizes, int n_in,
                              void* d_out, int out_size, void* d_ws, size_t ws_size,
                              hipStream_t stream) {
    const int*   idx  = (const int*)d_in[0];
    const float* emb  = (const float*)d_in[1];
    const float* linw = (const float*)d_in[2];
    const float* linb = (const float*)d_in[3];
    float* out = (float*)d_out;

    // ws layout: t f32 [N*D] = 32 MB; tb bf16 [N*D] = 16 MB; pi ushort [512*128*16] = 2 MB
    float*          t  = (float*)d_ws;
    unsigned short* tb = (unsigned short*)((char*)d_ws + (size_t)NN * DD * sizeof(float));
    unsigned short* pi = (unsigned short*)((char*)d_ws + (size_t)NN * DD * sizeof(float)
                                                       + (size_t)NN * DD * sizeof(unsigned short));

    (void)hipMemsetAsync(d_out, 0, (size_t)NN * (size_t)NN * sizeof(float), stream);

    k_transform<<<dim3(256 * 8), dim3(256), 0, stream>>>(idx, emb, linw, linb, t, tb);
    k_sim_topk<<<dim3((NN / 128) * NSPLIT), dim3(256), 0, stream>>>(tb, pi);
    k_rescore<<<dim3(NN / 4), dim3(256), 0, stream>>>(t, pi, out);
}